// Round 1
// 182.954 us; speedup vs baseline: 1.0276x; 1.0276x over previous
//
#include <hip/hip_runtime.h>

#define HH  512
#define WW  512
#define RAD 10
#define KK  21
#define SEG 16        // output rows per block
#define NROWS (SEG + 2 * RAD)   // 36 raw rows per block
#define LSTRIDE 540   // LDS row stride (floats): 532 used, 540 = 16B-aligned,
                      // mod 32 = 28 -> b128 start banks spread, ~conflict-free

// Fused separable Gaussian blur (21x21, sigma=3), reflect padding.
// v2: 512 threads/block (8 waves), 1 col/thread.
//   - LDS (34.5KB) allows 4 blocks/CU -> 32 waves/CU (100% cap, was 50%).
//   - rows[36] is 36 scalar VGPRs -> fits the 64-VGPR cap of
//     __launch_bounds__(512,8), so all 36 HBM loads are truly in flight
//     (the float2 variant needed 72 regs and got serialized at 52 VGPRs).
//   - Phase 2: exactly one (row, 16-col group) task per thread.
//   - XCD-contiguous block remap (3072 blocks % 8 == 0 -> bijective):
//     each XCD's private L2 keeps the halo rows of its own 12 images.
__global__ __launch_bounds__(512, 8) void gauss_blur_kernel(
    const float* __restrict__ x, float* __restrict__ out)
{
    // g[d] = exp(-d^2/18), w = g/sum(g); 2D kernel = outer(w,w) exactly.
    const float wt[KK] = {
        0.00051432f, 0.00147793f, 0.00380033f, 0.00874446f, 0.01800488f,
        0.03317359f, 0.05469399f, 0.08069227f, 0.10652936f, 0.12584957f,
        0.13303907f,
        0.12584957f, 0.10652936f, 0.08069227f, 0.05469399f, 0.03317359f,
        0.01800488f, 0.00874446f, 0.00380033f, 0.00147793f, 0.00051432f
    };

    __shared__ __align__(16) float vbuf[SEG * LSTRIDE];   // 34.56 KB

    // ---- XCD-contiguous remap: dispatch i -> XCD i%8 (round-robin), so
    // logical id (i&7)*384 + i>>3 gives each XCD a contiguous 384-block
    // (= 12 whole images) range. Pure bijection: 3072 % 8 == 0.
    const int bid = blockIdx.y * gridDim.x + blockIdx.x;
    const int cpx = (gridDim.x * gridDim.y) >> 3;          // 384
    const int lid = (bid & 7) * cpx + (bid >> 3);
    const int y0  = (lid & 31) * SEG;                      // gridDim.x == 32
    const int img = lid >> 5;

    const int t = threadIdx.x;                             // 0..511 = column

    const float* xim = x   + (size_t)img * (HH * WW);
    float*       oim = out + (size_t)img * (HH * WW);

    // ---------------- Phase 1: preload all 36 raw rows (36 loads in flight)
    float rows[NROWS];
    #pragma unroll
    for (int i = 0; i < NROWS; ++i) {
        int r  = y0 - RAD + i;
        int rr = r < 0 ? -r : (r > HH - 1 ? 2 * (HH - 1) - r : r);
        rows[i] = xim[rr * WW + t];
    }

    // ---------------- vertical blur -> LDS ----------------
    #pragma unroll
    for (int r = 0; r < SEG; ++r) {
        float v = 0.f;
        #pragma unroll
        for (int k = 0; k < KK; ++k)
            v = fmaf(wt[k], rows[r + k], v);
        float* vb = vbuf + r * LSTRIDE;
        vb[RAD + t] = v;
        // reflect pads in x
        if (t >= 1 && t <= RAD)                   vb[RAD - t] = v;
        if (t >= WW - 1 - RAD && t <= WW - 2)     vb[RAD + 2 * (WW - 1) - t] = v;
    }

    __syncthreads();   // the only barrier

    // ---------------- Phase 2: horizontal blur ----------------
    // 512 tasks, one per thread: row r = t & 15, col-group q = t >> 4 (16 cols).
    const int r = t & (SEG - 1);
    const int q = t >> 4;                                  // 0..31
    // padded window start = RAD + (q*16 - RAD) = q*16 -> 16B aligned
    const float* vr = vbuf + r * LSTRIDE + q * 16;

    float wnd[36];
    #pragma unroll
    for (int j = 0; j < 9; ++j) {
        float4 v4 = *(const float4*)(vr + 4 * j);
        wnd[4*j]   = v4.x; wnd[4*j+1] = v4.y;
        wnd[4*j+2] = v4.z; wnd[4*j+3] = v4.w;
    }

    float acc[16];
    #pragma unroll
    for (int j = 0; j < 16; ++j) {
        float s = 0.f;
        #pragma unroll
        for (int k = 0; k < KK; ++k)
            s = fmaf(wt[k], wnd[j + k], s);
        acc[j] = s;
    }

    float* op = oim + (size_t)(y0 + r) * WW + q * 16;
    #pragma unroll
    for (int j = 0; j < 4; ++j)
        *(float4*)(op + 4 * j) =
            make_float4(acc[4*j], acc[4*j+1], acc[4*j+2], acc[4*j+3]);
}

extern "C" void kernel_launch(void* const* d_in, const int* in_sizes, int n_in,
                              void* d_out, int out_size, void* d_ws, size_t ws_size,
                              hipStream_t stream) {
    const float* x = (const float*)d_in[0];
    float* out = (float*)d_out;
    const int n_img = in_sizes[0] / (HH * WW);     // 32*3 = 96
    dim3 grid(HH / SEG, n_img);                    // (32, 96) = 3072 blocks
    gauss_blur_kernel<<<grid, dim3(512), 0, stream>>>(x, out);
}